// Round 3
// baseline (472.386 us; speedup 1.0000x reference)
//
#include <hip/hip_runtime.h>
#include <cstdint>
#include <cstddef>

// B=2, S=2048, D=768, H=12, DH=64, T=64, R=50, FF=3072
// fp32 I/O, bf16 MFMA internals.
// R13: attn KV-split x2 (flash-decoding). R12 counters: MfmaUtil 17 + VALU 37
// = 53%, occupancy 24% (grid 768 = 3 blocks/CU was the binding limit; VGPR
// allows 7, LDS 5). KV-split keeps the staging:compute ratio fixed (R11
// lesson) while doubling blocks: grid (32,24,2), 1024 keys/block. Max-free
// streaming softmax makes the merge exact: partial unnormalized O (bf16,
// 2 slabs exactly filling d_out) + per-row l (fp32 in spare ws), then
// elementwise merge O=(p0+p1)/(l0+l1). Cross-attn: nsplit=1, old epilogue.
// GEMMs untouched.

typedef __bf16 bf16;
typedef __bf16 bf16x8 __attribute__((ext_vector_type(8)));
typedef __bf16 bf16x4 __attribute__((ext_vector_type(4)));
typedef __bf16 bf16x2 __attribute__((ext_vector_type(2)));
typedef float  floatx4 __attribute__((ext_vector_type(4)));

__device__ __forceinline__ void glds16(const bf16* g, bf16* l) {
  __builtin_amdgcn_global_load_lds((const __attribute__((address_space(1))) void*)g,
                                   (__attribute__((address_space(3))) void*)l, 16, 0, 0);
}

__device__ __forceinline__ float fexp2(float x) {
  float r;
  asm("v_exp_f32 %0, %1" : "=v"(r) : "v"(x));
  return r;
}

// ---------------------------------------------------------------------------
__global__ __launch_bounds__(256) void k_concat3(const float* __restrict__ a,
                                                 const float* __restrict__ b,
                                                 const float* __restrict__ c,
                                                 float* __restrict__ o, int seg) {
  int i = blockIdx.x * 256 + threadIdx.x;
  int s = i / seg, j = i - s * seg;
  const float* p = s == 0 ? a : (s == 1 ? b : c);
  o[i] = p[j];
}

__global__ void k_pad_tags(const float* __restrict__ tag, bf16* __restrict__ out) {
  int i = blockIdx.x * 256 + threadIdx.x;
  if (i < 64 * 768) out[i] = (bf16)tag[i];
  else if (i < 128 * 768) out[i] = (bf16)0.f;
}

// ---------------------------------------------------------------------------
__global__ __launch_bounds__(256) void k_transpose(const float* __restrict__ W,
                                                   bf16* __restrict__ Wt,
                                                   int K, int N) {
  __shared__ bf16 tile[64][72];
  int n0 = blockIdx.x * 64, k0 = blockIdx.y * 64;
  int t = threadIdx.x;
  int r = t >> 2, cg = (t & 3) * 16;
  const float* src = W + (size_t)(k0 + r) * N + n0 + cg;
  float tmp[16];
  *(float4*)&tmp[0]  = *(const float4*)(src);
  *(float4*)&tmp[4]  = *(const float4*)(src + 4);
  *(float4*)&tmp[8]  = *(const float4*)(src + 8);
  *(float4*)&tmp[12] = *(const float4*)(src + 12);
#pragma unroll
  for (int i = 0; i < 16; ++i) tile[r][cg + i] = (bf16)tmp[i];
  __syncthreads();
  bf16* dst = Wt + (size_t)(n0 + r) * K + k0 + cg;
#pragma unroll
  for (int g = 0; g < 2; ++g) {
    bf16x8 pack;
#pragma unroll
    for (int i = 0; i < 8; ++i) pack[i] = tile[cg + g * 8 + i][r];
    *(bf16x8*)(dst + g * 8) = pack;
  }
}

__global__ __launch_bounds__(256) void k_transpose4(const float* __restrict__ W0,
                                                    const float* __restrict__ W1,
                                                    const float* __restrict__ W2w,
                                                    const float* __restrict__ W3,
                                                    bf16* __restrict__ Wt) {
  __shared__ bf16 tile[64][72];
  int z = blockIdx.z;
  const float* W = z == 0 ? W0 : (z == 1 ? W1 : (z == 2 ? W2w : W3));
  bf16* dstb = Wt + (size_t)z * 768 * 768;
  int n0 = blockIdx.x * 64, k0 = blockIdx.y * 64;
  int t = threadIdx.x;
  int r = t >> 2, cg = (t & 3) * 16;
  const float* src = W + (size_t)(k0 + r) * 768 + n0 + cg;
  float tmp[16];
  *(float4*)&tmp[0]  = *(const float4*)(src);
  *(float4*)&tmp[4]  = *(const float4*)(src + 4);
  *(float4*)&tmp[8]  = *(const float4*)(src + 8);
  *(float4*)&tmp[12] = *(const float4*)(src + 12);
#pragma unroll
  for (int i = 0; i < 16; ++i) tile[r][cg + i] = (bf16)tmp[i];
  __syncthreads();
  bf16* dst = dstb + (size_t)(n0 + r) * 768 + k0 + cg;
#pragma unroll
  for (int g = 0; g < 2; ++g) {
    bf16x8 pack;
#pragma unroll
    for (int i = 0; i < 8; ++i) pack[i] = tile[cg + g * 8 + i][r];
    *(bf16x8*)(dst + g * 8) = pack;
  }
}

// ---------------------------------------------------------------------------
// GEMM: C[M,N] = A[M,K] @ Bt[N,K]^T + bias. BMx128 tile, KS BK=32 sub-tiles
// per barrier pair (KS=2 halves barrier count). glds width-16 staging.
// AF32: fp32 A cvt in regs (KS=1 only). CF32: fp32 C out.
template <int BM, int KS, bool AF32, bool CF32>
__global__ __launch_bounds__(256) void k_gemm(const void* __restrict__ Av,
                                              const bf16* __restrict__ Bt,
                                              const float* __restrict__ bias,
                                              void* __restrict__ Cv,
                                              int M, int N, int K, int act) {
  constexpr int MT = BM / 32;
  __shared__ bf16 As[KS][BM * 32];
  __shared__ bf16 Bs[KS][128 * 32];
  int tid = threadIdx.x;
  int lane = tid & 63, wave = tid >> 6;
  int l16 = lane & 15, quad = lane >> 4;
  int wm = wave & 1, wn = wave >> 1;
  int m0 = blockIdx.x * BM, n0 = blockIdx.y * 128;
  int arow = tid >> 2, acol = (tid & 3) * 8;
  int ldst = arow * 32 + acol;  // = tid*8 elems (lane-contiguous glds pattern)

  const bf16* Ab = (const bf16*)Av;
  const float* Af = (const float*)Av;
  const bf16* Ap = Ab + (size_t)(m0 + arow) * K + acol;
  const float* Apf = Af + (size_t)(m0 + arow) * K + acol;
  const bf16* Bp = Bt + (size_t)(n0 + arow) * K + acol;

  floatx4 acc[MT][4];
#pragma unroll
  for (int i = 0; i < MT; ++i)
#pragma unroll
    for (int j = 0; j < 4; ++j) acc[i][j] = floatx4{0.f, 0.f, 0.f, 0.f};

  float4 p0a, p0b, p1a, p1b;
  if constexpr (AF32) {
    p0a = *(const float4*)(Apf);
    p0b = *(const float4*)(Apf + 4);
    p1a = *(const float4*)(Apf + (size_t)64 * K);
    p1b = *(const float4*)(Apf + (size_t)64 * K + 4);
  }

  for (int k = 0; k < K; k += 32 * KS) {
    __syncthreads();
#pragma unroll
    for (int ks = 0; ks < KS; ++ks) {
      glds16(Bp + k + ks * 32, &Bs[ks][ldst]);
      glds16(Bp + (size_t)64 * K + k + ks * 32, &Bs[ks][ldst + 2048]);
    }
    if constexpr (AF32) {
      bf16x8 c0, c1;
      c0[0] = (bf16)p0a.x; c0[1] = (bf16)p0a.y; c0[2] = (bf16)p0a.z; c0[3] = (bf16)p0a.w;
      c0[4] = (bf16)p0b.x; c0[5] = (bf16)p0b.y; c0[6] = (bf16)p0b.z; c0[7] = (bf16)p0b.w;
      c1[0] = (bf16)p1a.x; c1[1] = (bf16)p1a.y; c1[2] = (bf16)p1a.z; c1[3] = (bf16)p1a.w;
      c1[4] = (bf16)p1b.x; c1[5] = (bf16)p1b.y; c1[6] = (bf16)p1b.z; c1[7] = (bf16)p1b.w;
      *(bf16x8*)&As[0][ldst] = c0;
      *(bf16x8*)&As[0][ldst + 2048] = c1;
    } else {
#pragma unroll
      for (int ks = 0; ks < KS; ++ks) {
        glds16(Ap + k + ks * 32, &As[ks][ldst]);
        if constexpr (BM == 128) glds16(Ap + (size_t)64 * K + k + ks * 32, &As[ks][ldst + 2048]);
      }
    }
    __syncthreads();
    if constexpr (AF32) {
      if (k + 32 < K) {
        p0a = *(const float4*)(Apf + k + 32);
        p0b = *(const float4*)(Apf + k + 36);
        p1a = *(const float4*)(Apf + (size_t)64 * K + k + 32);
        p1b = *(const float4*)(Apf + (size_t)64 * K + k + 36);
      }
    }
#pragma unroll
    for (int ks = 0; ks < KS; ++ks) {
      bf16x8 a_frag[MT], b_frag[4];
#pragma unroll
      for (int mt = 0; mt < MT; ++mt)
        a_frag[mt] = *(const bf16x8*)&As[ks][(wm * (BM / 2) + mt * 16 + l16) * 32 + quad * 8];
#pragma unroll
      for (int nt = 0; nt < 4; ++nt)
        b_frag[nt] = *(const bf16x8*)&Bs[ks][(wn * 64 + nt * 16 + l16) * 32 + quad * 8];
#pragma unroll
      for (int mt = 0; mt < MT; ++mt)
#pragma unroll
        for (int nt = 0; nt < 4; ++nt)
          acc[mt][nt] = __builtin_amdgcn_mfma_f32_16x16x32_bf16(a_frag[mt], b_frag[nt], acc[mt][nt], 0, 0, 0);
    }
  }

#pragma unroll
  for (int nt = 0; nt < 4; ++nt) {
    int col = n0 + wn * 64 + nt * 16 + l16;
    float bv = bias[col];
#pragma unroll
    for (int mt = 0; mt < MT; ++mt) {
#pragma unroll
      for (int r = 0; r < 4; ++r) {
        int row = m0 + wm * (BM / 2) + mt * 16 + quad * 4 + r;
        float v = acc[mt][nt][r] + bv;
        if (act) v = 0.5f * v * (1.f + erff(v * 0.70710678118654752f));
        if constexpr (CF32) ((float*)Cv)[(size_t)row * N + col] = v;
        else ((bf16*)Cv)[(size_t)row * N + col] = (bf16)v;
      }
    }
  }
}

// ---------------------------------------------------------------------------
// MFMA flash attention, max-free streaming softmax. QBLK=64 rows per block.
// Wave w: q-half qh=w&1 (32 rows), key-half kh=w>>1 (32 keys/chunk).
// Q pre-scaled by log2e/8, fragments direct from global (no Qs LDS stage).
// K/V global loads for chunk t+1 issued into regs during chunk t (T14).
// KV-split: blockIdx.z = split, keys [z*kvlen, (z+1)*kvlen). If Lbuf!=nullptr
// writes unnormalized partial O (slab z) + per-row l; else normalizes.
__global__ __launch_bounds__(256) void k_attn_mfma(const bf16* __restrict__ Q, int ldq,
                                                   const bf16* __restrict__ Kp,
                                                   const bf16* __restrict__ Vp, int ldkv,
                                                   bf16* __restrict__ O,
                                                   float* __restrict__ Lbuf,
                                                   int S, int kvlen,
                                                   long long kv_bstride, int bandR) {
  const int NH = 12;
  int qt = blockIdx.x, bh = blockIdx.y, z = blockIdx.z;
  int bb = bh / NH, h = bh % NH;
  int kv0 = z * kvlen;
  const bf16* Qb = Q + (size_t)bb * S * ldq + h * 64;
  const bf16* Kb = Kp + (size_t)bb * kv_bstride + h * 64;
  const bf16* Vb = Vp + (size_t)bb * kv_bstride + h * 64;
  size_t slab = (size_t)z * (size_t)(gridDim.y / NH) * S * 768;
  bf16* Ob = O + slab + (size_t)bb * S * 768 + h * 64;

  // LDS: Ks[64][72] @0 (9216), Vt[64][72] @9216 (9216), Psw 4x[32][40] @18432
  // (10240) = 28672 B total -> 5 blocks/CU LDS-wise (grid 6/CU, 5 resident).
  // Epilogue overlay: Obuf[64][66] f32 @0 (16896), l0[64] @16896 (fits 18432).
  __shared__ __align__(16) char smem[28672];
  bf16 (*Ks)[72] = (bf16(*)[72])(smem);
  bf16 (*Vt)[72] = (bf16(*)[72])(smem + 9216);
  float* Obuf = (float*)smem;
  float* l0_arr = (float*)(smem + 16896);

  int tid = threadIdx.x, wave = tid >> 6, lane = tid & 63;
  int quad = lane >> 4, l16 = lane & 15;
  int qh = wave & 1, kh = wave >> 1;
  bf16 (*Psw)[40] = (bf16(*)[40])(smem + 18432 + wave * 2560);

  const float C1 = 0.18033688f;   // log2(e)/8
  const float C2 = 1.44269504f;   // log2(e)

  int r = tid >> 2, cg = (tid & 3) * 16;  // K staging: 64 rows x 16 cols/lane
  int vk0 = 2 * (tid & 31);
  int vd0 = 8 * (tid >> 5);
  int vcol = (vk0 + 16 * (vd0 >> 4)) & 63;

  // Q fragments direct from global (once per block), pre-scaled by C1.
  bf16x8 aq[2][2];
#pragma unroll
  for (int mt = 0; mt < 2; ++mt) {
    const bf16* qsrc = Qb + (size_t)(qt * 64 + qh * 32 + mt * 16 + l16) * ldq;
#pragma unroll
    for (int ks = 0; ks < 2; ++ks) {
      bf16x8 t = *(const bf16x8*)(qsrc + ks * 32 + quad * 8);
#pragma unroll
      for (int e = 0; e < 8; ++e) t[e] = (bf16)((float)t[e] * C1);
      aq[mt][ks] = t;
    }
  }

  // prefetch regs for K/V chunk staging
  bf16x8 kr0, kr1, vr0, vr1;
  {
    const bf16* ksrc = Kb + (size_t)(kv0 + r) * ldkv + cg;
    kr0 = *(const bf16x8*)ksrc;
    kr1 = *(const bf16x8*)(ksrc + 8);
    const bf16* vsrc = Vb + (size_t)(kv0 + vk0) * ldkv + vd0;
    vr0 = *(const bf16x8*)vsrc;
    vr1 = *(const bf16x8*)(vsrc + ldkv);
  }

  float l_part[2][4];
  floatx4 acc[2][4];
#pragma unroll
  for (int mt = 0; mt < 2; ++mt)
#pragma unroll
    for (int j = 0; j < 4; ++j) {
      l_part[mt][j] = 0.f;
      acc[mt][j] = floatx4{0.f, 0.f, 0.f, 0.f};
    }

  int qi0 = qt * 64 + qh * 32 + quad * 4;
  int kv_end = kv0 + kvlen;

  for (int kc = kv0; kc < kv_end; kc += 64) {
    __syncthreads();
    // write staged chunk to LDS
    *(bf16x8*)&Ks[r][cg] = kr0;
    *(bf16x8*)&Ks[r][cg + 8] = kr1;
#pragma unroll
    for (int e = 0; e < 8; ++e) {
      bf16x2 p; p[0] = vr0[e]; p[1] = vr1[e];
      *(bf16x2*)&Vt[vd0 + e][vcol] = p;
    }
    // issue next chunk's loads (fly under this chunk's compute)
    if (kc + 64 < kv_end) {
      const bf16* ksrc = Kb + (size_t)(kc + 64 + r) * ldkv + cg;
      kr0 = *(const bf16x8*)ksrc;
      kr1 = *(const bf16x8*)(ksrc + 8);
      const bf16* vsrc = Vb + (size_t)(kc + 64 + vk0) * ldkv + vd0;
      vr0 = *(const bf16x8*)vsrc;
      vr1 = *(const bf16x8*)(vsrc + ldkv);
    }
    __syncthreads();

    floatx4 s[2][2];
#pragma unroll
    for (int kt = 0; kt < 2; ++kt) {
      bf16x8 bk0 = *(const bf16x8*)&Ks[kh * 32 + kt * 16 + l16][quad * 8];
      bf16x8 bk1 = *(const bf16x8*)&Ks[kh * 32 + kt * 16 + l16][32 + quad * 8];
#pragma unroll
      for (int mt = 0; mt < 2; ++mt) {
        floatx4 c = {0.f, 0.f, 0.f, 0.f};
        c = __builtin_amdgcn_mfma_f32_16x16x32_bf16(aq[mt][0], bk0, c, 0, 0, 0);
        c = __builtin_amdgcn_mfma_f32_16x16x32_bf16(aq[mt][1], bk1, c, 0, 0, 0);
        s[mt][kt] = c;
      }
    }

    bool masked = (bandR >= 0) && (kc <= qt * 64 + 63 + bandR) &&
                  (kc + 63 >= qt * 64 - bandR);
    if (masked) {
#pragma unroll
      for (int kt = 0; kt < 2; ++kt) {
        int kj = kc + kh * 32 + kt * 16 + l16;
        int colp = (kt * 16 + l16 + 8 * quad) & 31;
#pragma unroll
        for (int mt = 0; mt < 2; ++mt)
#pragma unroll
          for (int rr = 0; rr < 4; ++rr) {
            int d = qi0 + mt * 16 + rr - kj; if (d < 0) d = -d;
            float e = fexp2(s[mt][kt][rr] + (d <= bandR ? C2 : 0.f));
            l_part[mt][rr] += e;
            Psw[mt * 16 + quad * 4 + rr][colp] = (bf16)e;
          }
      }
    } else {
#pragma unroll
      for (int kt = 0; kt < 2; ++kt) {
        int colp = (kt * 16 + l16 + 8 * quad) & 31;
#pragma unroll
        for (int mt = 0; mt < 2; ++mt)
#pragma unroll
          for (int rr = 0; rr < 4; ++rr) {
            float e = fexp2(s[mt][kt][rr]);
            l_part[mt][rr] += e;
            Psw[mt * 16 + quad * 4 + rr][colp] = (bf16)e;
          }
      }
    }

    bf16x8 ap[2];
#pragma unroll
    for (int mt = 0; mt < 2; ++mt)
      ap[mt] = *(const bf16x8*)&Psw[mt * 16 + l16][8 * ((quad + (l16 >> 2)) & 3)];
#pragma unroll
    for (int nt = 0; nt < 4; ++nt) {
      bf16x8 bv = *(const bf16x8*)&Vt[nt * 16 + l16][(kh * 32 + quad * 8 + 16 * nt) & 63];
#pragma unroll
      for (int mt = 0; mt < 2; ++mt)
        acc[mt][nt] = __builtin_amdgcn_mfma_f32_16x16x32_bf16(ap[mt], bv, acc[mt][nt], 0, 0, 0);
    }
  }

  // ---- epilogue: reduce l within quad, combine key-halves via LDS ----
  float lr[2][4];
#pragma unroll
  for (int mt = 0; mt < 2; ++mt)
#pragma unroll
    for (int rr = 0; rr < 4; ++rr) {
      float t = l_part[mt][rr];
      t += __shfl_xor(t, 1);
      t += __shfl_xor(t, 2);
      t += __shfl_xor(t, 4);
      t += __shfl_xor(t, 8);
      lr[mt][rr] = t;
    }
  __syncthreads();
  if (kh == 0) {
#pragma unroll
    for (int mt = 0; mt < 2; ++mt)
#pragma unroll
      for (int nt = 0; nt < 4; ++nt)
#pragma unroll
        for (int rr = 0; rr < 4; ++rr)
          Obuf[(qh * 32 + mt * 16 + quad * 4 + rr) * 66 + nt * 16 + l16] = acc[mt][nt][rr];
    if (l16 == 0) {
#pragma unroll
      for (int mt = 0; mt < 2; ++mt)
#pragma unroll
        for (int rr = 0; rr < 4; ++rr)
          l0_arr[qh * 32 + mt * 16 + quad * 4 + rr] = lr[mt][rr];
    }
  }
  __syncthreads();
  if (kh == 1) {
#pragma unroll
    for (int mt = 0; mt < 2; ++mt)
#pragma unroll
      for (int rr = 0; rr < 4; ++rr) {
        int ql = qh * 32 + mt * 16 + quad * 4 + rr;
        float lt = lr[mt][rr] + l0_arr[ql];
        int qrow = qt * 64 + ql;
        if (Lbuf) {
          if (l16 == 0)
            Lbuf[((size_t)z * gridDim.y + bh) * S + qrow] = lt;
#pragma unroll
          for (int nt = 0; nt < 4; ++nt) {
            float o = acc[mt][nt][rr] + Obuf[ql * 66 + nt * 16 + l16];
            Ob[(size_t)qrow * 768 + nt * 16 + l16] = (bf16)o;
          }
        } else {
#pragma unroll
          for (int nt = 0; nt < 4; ++nt) {
            float o = (acc[mt][nt][rr] + Obuf[ql * 66 + nt * 16 + l16]) / lt;
            Ob[(size_t)qrow * 768 + nt * 16 + l16] = (bf16)o;
          }
        }
      }
  }
}

// ---------------------------------------------------------------------------
// Merge 2 KV-split partials: O = (p0 + p1) / (l0 + l1), in place on slab 0.
// Layout: O slabs [2][4096][768] bf16; Lbuf [2][24][2048] f32.
__global__ __launch_bounds__(256) void k_attn_merge(bf16* __restrict__ O,
                                                    const float* __restrict__ Lbuf) {
  int i = blockIdx.x * 256 + threadIdx.x;  // 8-elem group; 96 groups/row
  int r = i / 96;                          // global row 0..4095
  int c = (i - r * 96) * 8;                // col 0..760
  size_t base = (size_t)r * 768 + c;
  int bh = (r >> 11) * 12 + (c >> 6);
  int row = r & 2047;
  float l = Lbuf[(size_t)bh * 2048 + row] + Lbuf[(size_t)(24 + bh) * 2048 + row];
  float inv = 1.f / l;
  bf16x8 p0 = *(const bf16x8*)(O + base);
  bf16x8 p1 = *(const bf16x8*)(O + (size_t)4096 * 768 + base);
  bf16x8 o;
#pragma unroll
  for (int e = 0; e < 8; ++e) o[e] = (bf16)(((float)p0[e] + (float)p1[e]) * inv);
  *(bf16x8*)(O + base) = o;
}

// ---------------------------------------------------------------------------
template <typename TY, typename TR, typename TO>
__global__ __launch_bounds__(256) void k_add_ln(const TY* __restrict__ Y,
                                                const TR* __restrict__ X,
                                                const float* __restrict__ g,
                                                const float* __restrict__ b,
                                                TO* __restrict__ out) {
  int wave = threadIdx.x >> 6, lane = threadIdx.x & 63;
  int row = blockIdx.x * 4 + wave;
  const TY* y = Y + (size_t)row * 768;
  const TR* x = X + (size_t)row * 768;
  float v[12];
  float s = 0.f, s2 = 0.f;
#pragma unroll
  for (int c = 0; c < 3; ++c) {
    int idx = c * 256 + lane * 4;
    float yv[4], xv[4];
    if constexpr (__is_same(TY, float)) {
      float4 t = *(const float4*)(y + idx);
      yv[0] = t.x; yv[1] = t.y; yv[2] = t.z; yv[3] = t.w;
    } else {
      bf16x4 t = *(const bf16x4*)(y + idx);
#pragma unroll
      for (int i = 0; i < 4; ++i) yv[i] = (float)t[i];
    }
    if constexpr (__is_same(TR, float)) {
      float4 t = *(const float4*)(x + idx);
      xv[0] = t.x; xv[1] = t.y; xv[2] = t.z; xv[3] = t.w;
    } else {
      bf16x4 t = *(const bf16x4*)(x + idx);
#pragma unroll
      for (int i = 0; i < 4; ++i) xv[i] = (float)t[i];
    }
#pragma unroll
    for (int i = 0; i < 4; ++i) {
      float t = yv[i] + xv[i];
      v[c * 4 + i] = t; s += t; s2 += t * t;
    }
  }
#pragma unroll
  for (int off = 32; off > 0; off >>= 1) { s += __shfl_xor(s, off); s2 += __shfl_xor(s2, off); }
  float mean = s * (1.f / 768.f);
  float var = fmaxf(s2 * (1.f / 768.f) - mean * mean, 0.f);
  float inv = rsqrtf(var + 1e-12f);
  TO* o = out + (size_t)row * 768;
#pragma unroll
  for (int c = 0; c < 3; ++c) {
    int idx = c * 256 + lane * 4;
    float4 gv = *(const float4*)(g + idx);
    float4 bv = *(const float4*)(b + idx);
    float r0 = (v[c * 4 + 0] - mean) * inv * gv.x + bv.x;
    float r1 = (v[c * 4 + 1] - mean) * inv * gv.y + bv.y;
    float r2 = (v[c * 4 + 2] - mean) * inv * gv.z + bv.z;
    float r3 = (v[c * 4 + 3] - mean) * inv * gv.w + bv.w;
    if constexpr (__is_same(TO, float)) {
      float4 ov = {r0, r1, r2, r3};
      *(float4*)(o + idx) = ov;
    } else {
      bf16x4 ov;
      ov[0] = (bf16)r0; ov[1] = (bf16)r1; ov[2] = (bf16)r2; ov[3] = (bf16)r3;
      *(bf16x4*)(o + idx) = ov;
    }
  }
}

// ---------------------------------------------------------------------------
extern "C" void kernel_launch(void* const* d_in, const int* in_sizes, int n_in,
                              void* d_out, int out_size, void* d_ws, size_t ws_size,
                              hipStream_t stream) {
  (void)in_sizes; (void)n_in; (void)out_size; (void)ws_size;
  const float* X     = (const float*)d_in[0];
  const float* tag   = (const float*)d_in[1];
  const float* sa_wq = (const float*)d_in[2];
  const float* sa_bq = (const float*)d_in[3];
  const float* sa_wk = (const float*)d_in[4];
  const float* sa_bk = (const float*)d_in[5];
  const float* sa_wv = (const float*)d_in[6];
  const float* sa_bv = (const float*)d_in[7];
  const float* sa_wo = (const float*)d_in[8];
  const float* sa_bo = (const float*)d_in[9];
  const float* sa_lg = (const float*)d_in[10];
  const float* sa_lb = (const float*)d_in[11];
  const float* ca_wq = (const float*)d_in[12];
  const float* ca_bq = (const float*)d_in[13];
  const float* ca_wk = (const float*)d_in[14];
  const float* ca_bk = (const float*)d_in[15];
  const float* ca_wv = (const float*)d_in[16];
  const float* ca_bv = (const float*)d_in[17];
  const float* ca_wo = (const float*)d_in[18];
  const float* ca_bo = (const float*)d_in[19];
  const float* ca_lg = (const float*)d_in[20];
  const float* ca_lb = (const float*)d_in[21];
  const float* ff_w1 = (const float*)d_in[22];
  const float* ff_b1 = (const float*)d_in[23];
  const float* ff_w2 = (const float*)d_in[24];
  const float* ff_b2 = (const float*)d_in[25];
  const float* ff_lg = (const float*)d_in[26];
  const float* ff_lb = (const float*)d_in[27];

  float* outf = (float*)d_out;
  bf16* outb = (bf16*)d_out;
  const size_t SLOT = (size_t)4096 * 768;

  // ---- ws: 34.60 MB ----
  bf16* BIG   = (bf16*)d_ws;                    // 4096x2304
  bf16* slotA = BIG + (size_t)4096 * 2304;      // residual chain
  bf16* Wall  = slotA + SLOT;                   // 3072x768
  bf16* W2    = Wall + (size_t)3072 * 768;      // 768x3072
  bf16* tagp  = W2;
  bf16* k2v2  = W2 + (size_t)128 * 768;
  float* bQKV = (float*)(W2 + (size_t)128 * 768 + (size_t)128 * 1536);
  float* bKV2 = bQKV + 2304;
  float* Lbuf = bKV2 + 1536;                    // [2][24][2048] f32, self-attn only

  dim3 blk(256);

  k_concat3<<<dim3(9), blk, 0, stream>>>(sa_bq, sa_bk, sa_bv, bQKV, 768);
  k_concat3<<<dim3(6), blk, 0, stream>>>(ca_bk, ca_bv, nullptr, bKV2, 768);
  k_pad_tags<<<dim3(384), blk, 0, stream>>>(tag, tagp);

  // ---- self-attention ----
  k_transpose4<<<dim3(12, 12, 4), blk, 0, stream>>>(sa_wq, sa_wk, sa_wv, sa_wo, Wall);
  k_gemm<128, 1, true, false><<<dim3(32, 18), blk, 0, stream>>>(X, Wall, bQKV, BIG,
                                                                4096, 2304, 768, 0);  // QKV
  // KV-split x2: partial slabs fill d_out exactly (2 x 4096x768 bf16).
  k_attn_mfma<<<dim3(32, 24, 2), blk, 0, stream>>>(BIG, 2304, BIG + 768, BIG + 1536, 2304,
                                                   outb, Lbuf, 2048, 1024,
                                                   (long long)2048 * 2304, 50);
  k_attn_merge<<<dim3(1536), blk, 0, stream>>>(outb, Lbuf);
  k_gemm<64, 2, false, false><<<dim3(64, 6), blk, 0, stream>>>(outb, Wall + (size_t)2304 * 768,
                                                               sa_bo, slotA, 4096, 768, 768, 0);  // y1
  k_add_ln<bf16, float, bf16><<<dim3(1024), blk, 0, stream>>>(slotA, X, sa_lg, sa_lb, slotA);

  // ---- cross-attention ----
  k_transpose4<<<dim3(12, 12, 4), blk, 0, stream>>>(ca_wq, ca_wk, ca_wv, ca_wo, Wall);
  k_gemm<64, 2, false, false><<<dim3(64, 6), blk, 0, stream>>>(slotA, Wall, ca_bq, BIG,
                                                               4096, 768, 768, 0);  // Q2
  k_gemm<64, 2, false, false><<<dim3(2, 12), blk, 0, stream>>>(tagp, Wall + (size_t)768 * 768,
                                                               bKV2, k2v2, 128, 1536, 768, 0);  // K2V2
  k_attn_mfma<<<dim3(32, 24, 1), blk, 0, stream>>>(BIG, 768, k2v2, k2v2 + 768, 1536,
                                                   outb, nullptr, 2048, 64, 0, -1);
  k_gemm<64, 2, false, false><<<dim3(64, 6), blk, 0, stream>>>(outb, Wall + (size_t)2304 * 768,
                                                               ca_bo, BIG + SLOT, 4096, 768, 768, 0);  // y2
  k_add_ln<bf16, bf16, bf16><<<dim3(1024), blk, 0, stream>>>(BIG + SLOT, slotA, ca_lg, ca_lb, slotA);

  // ---- FFN: 2 M-chunks of 2048 rows via BIG ----
  k_transpose<<<dim3(48, 12), blk, 0, stream>>>(ff_w1, Wall, 768, 3072);  // ff1t [3072][768]
  k_transpose<<<dim3(12, 48), blk, 0, stream>>>(ff_w2, W2, 3072, 768);    // ff2t [768][3072]
  for (int mc = 0; mc < 2; ++mc) {
    const bf16* a2 = slotA + (size_t)mc * 2048 * 768;
    float* yo = outf + (size_t)mc * 2048 * 768;
    k_gemm<128, 2, false, false><<<dim3(16, 24), blk, 0, stream>>>(a2, Wall, ff_b1, BIG,
                                                                   2048, 3072, 768, 1);  // gelu inter
    k_gemm<64, 2, false, true><<<dim3(32, 6), blk, 0, stream>>>(BIG, W2, ff_b2, yo,
                                                                2048, 768, 3072, 0);     // y3 fp32
    k_add_ln<float, bf16, float><<<dim3(512), blk, 0, stream>>>(yo, a2, ff_lg, ff_lb, yo);
  }
}

// Round 4
// 465.680 us; speedup vs baseline: 1.0144x; 1.0144x over previous
//
#include <hip/hip_runtime.h>
#include <cstdint>
#include <cstddef>

// B=2, S=2048, D=768, H=12, DH=64, T=64, R=50, FF=3072
// fp32 I/O, bf16 MFMA internals.
// R14: KV-split reverted (R13: occupancy didn't move, merge+write traffic
// cost ~4us net). Attn: LDS double-buffer K/V -> ONE barrier per chunk
// (was 2). Write chunk c -> buf[c&1]; issue chunk c+1 global loads; barrier;
// compute buf[c&1]; no trailing barrier. Cross-buffer writes can't race
// (different buffer; iter c+1's barrier fences reuse at c+2). Waves skew ->
// s_setprio(1) around MFMA clusters has role diversity to arbitrate (T5).
// LDS 47104 B = 3 blocks/CU (matches nsplit=1 grid cap of 3). GEMMs untouched.

typedef __bf16 bf16;
typedef __bf16 bf16x8 __attribute__((ext_vector_type(8)));
typedef __bf16 bf16x4 __attribute__((ext_vector_type(4)));
typedef __bf16 bf16x2 __attribute__((ext_vector_type(2)));
typedef float  floatx4 __attribute__((ext_vector_type(4)));

__device__ __forceinline__ void glds16(const bf16* g, bf16* l) {
  __builtin_amdgcn_global_load_lds((const __attribute__((address_space(1))) void*)g,
                                   (__attribute__((address_space(3))) void*)l, 16, 0, 0);
}

__device__ __forceinline__ float fexp2(float x) {
  float r;
  asm("v_exp_f32 %0, %1" : "=v"(r) : "v"(x));
  return r;
}

// ---------------------------------------------------------------------------
__global__ __launch_bounds__(256) void k_concat3(const float* __restrict__ a,
                                                 const float* __restrict__ b,
                                                 const float* __restrict__ c,
                                                 float* __restrict__ o, int seg) {
  int i = blockIdx.x * 256 + threadIdx.x;
  int s = i / seg, j = i - s * seg;
  const float* p = s == 0 ? a : (s == 1 ? b : c);
  o[i] = p[j];
}

__global__ void k_pad_tags(const float* __restrict__ tag, bf16* __restrict__ out) {
  int i = blockIdx.x * 256 + threadIdx.x;
  if (i < 64 * 768) out[i] = (bf16)tag[i];
  else if (i < 128 * 768) out[i] = (bf16)0.f;
}

// ---------------------------------------------------------------------------
__global__ __launch_bounds__(256) void k_transpose(const float* __restrict__ W,
                                                   bf16* __restrict__ Wt,
                                                   int K, int N) {
  __shared__ bf16 tile[64][72];
  int n0 = blockIdx.x * 64, k0 = blockIdx.y * 64;
  int t = threadIdx.x;
  int r = t >> 2, cg = (t & 3) * 16;
  const float* src = W + (size_t)(k0 + r) * N + n0 + cg;
  float tmp[16];
  *(float4*)&tmp[0]  = *(const float4*)(src);
  *(float4*)&tmp[4]  = *(const float4*)(src + 4);
  *(float4*)&tmp[8]  = *(const float4*)(src + 8);
  *(float4*)&tmp[12] = *(const float4*)(src + 12);
#pragma unroll
  for (int i = 0; i < 16; ++i) tile[r][cg + i] = (bf16)tmp[i];
  __syncthreads();
  bf16* dst = Wt + (size_t)(n0 + r) * K + k0 + cg;
#pragma unroll
  for (int g = 0; g < 2; ++g) {
    bf16x8 pack;
#pragma unroll
    for (int i = 0; i < 8; ++i) pack[i] = tile[cg + g * 8 + i][r];
    *(bf16x8*)(dst + g * 8) = pack;
  }
}

__global__ __launch_bounds__(256) void k_transpose4(const float* __restrict__ W0,
                                                    const float* __restrict__ W1,
                                                    const float* __restrict__ W2w,
                                                    const float* __restrict__ W3,
                                                    bf16* __restrict__ Wt) {
  __shared__ bf16 tile[64][72];
  int z = blockIdx.z;
  const float* W = z == 0 ? W0 : (z == 1 ? W1 : (z == 2 ? W2w : W3));
  bf16* dstb = Wt + (size_t)z * 768 * 768;
  int n0 = blockIdx.x * 64, k0 = blockIdx.y * 64;
  int t = threadIdx.x;
  int r = t >> 2, cg = (t & 3) * 16;
  const float* src = W + (size_t)(k0 + r) * 768 + n0 + cg;
  float tmp[16];
  *(float4*)&tmp[0]  = *(const float4*)(src);
  *(float4*)&tmp[4]  = *(const float4*)(src + 4);
  *(float4*)&tmp[8]  = *(const float4*)(src + 8);
  *(float4*)&tmp[12] = *(const float4*)(src + 12);
#pragma unroll
  for (int i = 0; i < 16; ++i) tile[r][cg + i] = (bf16)tmp[i];
  __syncthreads();
  bf16* dst = dstb + (size_t)(n0 + r) * 768 + k0 + cg;
#pragma unroll
  for (int g = 0; g < 2; ++g) {
    bf16x8 pack;
#pragma unroll
    for (int i = 0; i < 8; ++i) pack[i] = tile[cg + g * 8 + i][r];
    *(bf16x8*)(dst + g * 8) = pack;
  }
}

// ---------------------------------------------------------------------------
// GEMM: C[M,N] = A[M,K] @ Bt[N,K]^T + bias. BMx128 tile, KS BK=32 sub-tiles
// per barrier pair (KS=2 halves barrier count). glds width-16 staging.
// AF32: fp32 A cvt in regs (KS=1 only). CF32: fp32 C out.
template <int BM, int KS, bool AF32, bool CF32>
__global__ __launch_bounds__(256) void k_gemm(const void* __restrict__ Av,
                                              const bf16* __restrict__ Bt,
                                              const float* __restrict__ bias,
                                              void* __restrict__ Cv,
                                              int M, int N, int K, int act) {
  constexpr int MT = BM / 32;
  __shared__ bf16 As[KS][BM * 32];
  __shared__ bf16 Bs[KS][128 * 32];
  int tid = threadIdx.x;
  int lane = tid & 63, wave = tid >> 6;
  int l16 = lane & 15, quad = lane >> 4;
  int wm = wave & 1, wn = wave >> 1;
  int m0 = blockIdx.x * BM, n0 = blockIdx.y * 128;
  int arow = tid >> 2, acol = (tid & 3) * 8;
  int ldst = arow * 32 + acol;  // = tid*8 elems (lane-contiguous glds pattern)

  const bf16* Ab = (const bf16*)Av;
  const float* Af = (const float*)Av;
  const bf16* Ap = Ab + (size_t)(m0 + arow) * K + acol;
  const float* Apf = Af + (size_t)(m0 + arow) * K + acol;
  const bf16* Bp = Bt + (size_t)(n0 + arow) * K + acol;

  floatx4 acc[MT][4];
#pragma unroll
  for (int i = 0; i < MT; ++i)
#pragma unroll
    for (int j = 0; j < 4; ++j) acc[i][j] = floatx4{0.f, 0.f, 0.f, 0.f};

  float4 p0a, p0b, p1a, p1b;
  if constexpr (AF32) {
    p0a = *(const float4*)(Apf);
    p0b = *(const float4*)(Apf + 4);
    p1a = *(const float4*)(Apf + (size_t)64 * K);
    p1b = *(const float4*)(Apf + (size_t)64 * K + 4);
  }

  for (int k = 0; k < K; k += 32 * KS) {
    __syncthreads();
#pragma unroll
    for (int ks = 0; ks < KS; ++ks) {
      glds16(Bp + k + ks * 32, &Bs[ks][ldst]);
      glds16(Bp + (size_t)64 * K + k + ks * 32, &Bs[ks][ldst + 2048]);
    }
    if constexpr (AF32) {
      bf16x8 c0, c1;
      c0[0] = (bf16)p0a.x; c0[1] = (bf16)p0a.y; c0[2] = (bf16)p0a.z; c0[3] = (bf16)p0a.w;
      c0[4] = (bf16)p0b.x; c0[5] = (bf16)p0b.y; c0[6] = (bf16)p0b.z; c0[7] = (bf16)p0b.w;
      c1[0] = (bf16)p1a.x; c1[1] = (bf16)p1a.y; c1[2] = (bf16)p1a.z; c1[3] = (bf16)p1a.w;
      c1[4] = (bf16)p1b.x; c1[5] = (bf16)p1b.y; c1[6] = (bf16)p1b.z; c1[7] = (bf16)p1b.w;
      *(bf16x8*)&As[0][ldst] = c0;
      *(bf16x8*)&As[0][ldst + 2048] = c1;
    } else {
#pragma unroll
      for (int ks = 0; ks < KS; ++ks) {
        glds16(Ap + k + ks * 32, &As[ks][ldst]);
        if constexpr (BM == 128) glds16(Ap + (size_t)64 * K + k + ks * 32, &As[ks][ldst + 2048]);
      }
    }
    __syncthreads();
    if constexpr (AF32) {
      if (k + 32 < K) {
        p0a = *(const float4*)(Apf + k + 32);
        p0b = *(const float4*)(Apf + k + 36);
        p1a = *(const float4*)(Apf + (size_t)64 * K + k + 32);
        p1b = *(const float4*)(Apf + (size_t)64 * K + k + 36);
      }
    }
#pragma unroll
    for (int ks = 0; ks < KS; ++ks) {
      bf16x8 a_frag[MT], b_frag[4];
#pragma unroll
      for (int mt = 0; mt < MT; ++mt)
        a_frag[mt] = *(const bf16x8*)&As[ks][(wm * (BM / 2) + mt * 16 + l16) * 32 + quad * 8];
#pragma unroll
      for (int nt = 0; nt < 4; ++nt)
        b_frag[nt] = *(const bf16x8*)&Bs[ks][(wn * 64 + nt * 16 + l16) * 32 + quad * 8];
#pragma unroll
      for (int mt = 0; mt < MT; ++mt)
#pragma unroll
        for (int nt = 0; nt < 4; ++nt)
          acc[mt][nt] = __builtin_amdgcn_mfma_f32_16x16x32_bf16(a_frag[mt], b_frag[nt], acc[mt][nt], 0, 0, 0);
    }
  }

#pragma unroll
  for (int nt = 0; nt < 4; ++nt) {
    int col = n0 + wn * 64 + nt * 16 + l16;
    float bv = bias[col];
#pragma unroll
    for (int mt = 0; mt < MT; ++mt) {
#pragma unroll
      for (int r = 0; r < 4; ++r) {
        int row = m0 + wm * (BM / 2) + mt * 16 + quad * 4 + r;
        float v = acc[mt][nt][r] + bv;
        if (act) v = 0.5f * v * (1.f + erff(v * 0.70710678118654752f));
        if constexpr (CF32) ((float*)Cv)[(size_t)row * N + col] = v;
        else ((bf16*)Cv)[(size_t)row * N + col] = (bf16)v;
      }
    }
  }
}

// ---------------------------------------------------------------------------
// MFMA flash attention, max-free streaming softmax. QBLK=64 rows per block.
// Wave w: q-half qh=w&1 (32 rows), key-half kh=w>>1 (32 keys/chunk).
// Q pre-scaled by log2e/8, fragments direct from global (no Qs LDS stage).
// K/V double-buffered in LDS: write chunk c -> buf[c&1], issue c+1 loads,
// ONE barrier, compute; no trailing barrier (iter c+1's barrier fences
// buffer reuse at c+2). s_setprio(1) around MFMA clusters (waves skew).
__global__ __launch_bounds__(256) void k_attn_mfma(const bf16* __restrict__ Q, int ldq,
                                                   const bf16* __restrict__ Kp,
                                                   const bf16* __restrict__ Vp, int ldkv,
                                                   bf16* __restrict__ O,
                                                   int S, int Skv,
                                                   long long kv_bstride, int bandR) {
  const int NH = 12;
  int qt = blockIdx.x, bh = blockIdx.y;
  int bb = bh / NH, h = bh % NH;
  const bf16* Qb = Q + (size_t)bb * S * ldq + h * 64;
  const bf16* Kb = Kp + (size_t)bb * kv_bstride + h * 64;
  const bf16* Vb = Vp + (size_t)bb * kv_bstride + h * 64;
  bf16* Ob = O + (size_t)bb * S * 768 + h * 64;

  // LDS: Ks[2][64][72] @0 (18432), Vt[2][64][72] @18432 (18432),
  // Psw 4x[32][40] @36864 (10240) = 47104 B -> 3 blocks/CU (= grid cap).
  // Epilogue overlay: Obuf[64][66] f32 @0 (16896), l0[64] @16896.
  __shared__ __align__(16) char smem[47104];
  float* Obuf = (float*)smem;
  float* l0_arr = (float*)(smem + 16896);

  int tid = threadIdx.x, wave = tid >> 6, lane = tid & 63;
  int quad = lane >> 4, l16 = lane & 15;
  int qh = wave & 1, kh = wave >> 1;
  bf16 (*Psw)[40] = (bf16(*)[40])(smem + 36864 + wave * 2560);

  const float C1 = 0.18033688f;   // log2(e)/8
  const float C2 = 1.44269504f;   // log2(e)

  int r = tid >> 2, cg = (tid & 3) * 16;  // K staging: 64 rows x 16 cols/lane
  int vk0 = 2 * (tid & 31);
  int vd0 = 8 * (tid >> 5);
  int vcol = (vk0 + 16 * (vd0 >> 4)) & 63;

  // Q fragments direct from global (once per block), pre-scaled by C1.
  bf16x8 aq[2][2];
#pragma unroll
  for (int mt = 0; mt < 2; ++mt) {
    const bf16* qsrc = Qb + (size_t)(qt * 64 + qh * 32 + mt * 16 + l16) * ldq;
#pragma unroll
    for (int ks = 0; ks < 2; ++ks) {
      bf16x8 t = *(const bf16x8*)(qsrc + ks * 32 + quad * 8);
#pragma unroll
      for (int e = 0; e < 8; ++e) t[e] = (bf16)((float)t[e] * C1);
      aq[mt][ks] = t;
    }
  }

  // prefetch regs for K/V chunk staging
  bf16x8 kr0, kr1, vr0, vr1;
  {
    const bf16* ksrc = Kb + (size_t)r * ldkv + cg;
    kr0 = *(const bf16x8*)ksrc;
    kr1 = *(const bf16x8*)(ksrc + 8);
    const bf16* vsrc = Vb + (size_t)vk0 * ldkv + vd0;
    vr0 = *(const bf16x8*)vsrc;
    vr1 = *(const bf16x8*)(vsrc + ldkv);
  }

  float l_part[2][4];
  floatx4 acc[2][4];
#pragma unroll
  for (int mt = 0; mt < 2; ++mt)
#pragma unroll
    for (int j = 0; j < 4; ++j) {
      l_part[mt][j] = 0.f;
      acc[mt][j] = floatx4{0.f, 0.f, 0.f, 0.f};
    }

  int qi0 = qt * 64 + qh * 32 + quad * 4;

  for (int kc = 0; kc < Skv; kc += 64) {
    int cur = (kc >> 6) & 1;
    bf16 (*Ks)[72] = (bf16(*)[72])(smem + cur * 9216);
    bf16 (*Vt)[72] = (bf16(*)[72])(smem + 18432 + cur * 9216);
    // write staged chunk to buf[cur] (prior reads of buf[cur] fenced by the
    // barrier of iter c-1)
    *(bf16x8*)&Ks[r][cg] = kr0;
    *(bf16x8*)&Ks[r][cg + 8] = kr1;
#pragma unroll
    for (int e = 0; e < 8; ++e) {
      bf16x2 p; p[0] = vr0[e]; p[1] = vr1[e];
      *(bf16x2*)&Vt[vd0 + e][vcol] = p;
    }
    // issue next chunk's loads (fly under this chunk's compute)
    if (kc + 64 < Skv) {
      const bf16* ksrc = Kb + (size_t)(kc + 64 + r) * ldkv + cg;
      kr0 = *(const bf16x8*)ksrc;
      kr1 = *(const bf16x8*)(ksrc + 8);
      const bf16* vsrc = Vb + (size_t)(kc + 64 + vk0) * ldkv + vd0;
      vr0 = *(const bf16x8*)vsrc;
      vr1 = *(const bf16x8*)(vsrc + ldkv);
    }
    __syncthreads();

    floatx4 s[2][2];
    __builtin_amdgcn_s_setprio(1);
#pragma unroll
    for (int kt = 0; kt < 2; ++kt) {
      bf16x8 bk0 = *(const bf16x8*)&Ks[kh * 32 + kt * 16 + l16][quad * 8];
      bf16x8 bk1 = *(const bf16x8*)&Ks[kh * 32 + kt * 16 + l16][32 + quad * 8];
#pragma unroll
      for (int mt = 0; mt < 2; ++mt) {
        floatx4 c = {0.f, 0.f, 0.f, 0.f};
        c = __builtin_amdgcn_mfma_f32_16x16x32_bf16(aq[mt][0], bk0, c, 0, 0, 0);
        c = __builtin_amdgcn_mfma_f32_16x16x32_bf16(aq[mt][1], bk1, c, 0, 0, 0);
        s[mt][kt] = c;
      }
    }
    __builtin_amdgcn_s_setprio(0);

    bool masked = (bandR >= 0) && (kc <= qt * 64 + 63 + bandR) &&
                  (kc + 63 >= qt * 64 - bandR);
    if (masked) {
#pragma unroll
      for (int kt = 0; kt < 2; ++kt) {
        int kj = kc + kh * 32 + kt * 16 + l16;
        int colp = (kt * 16 + l16 + 8 * quad) & 31;
#pragma unroll
        for (int mt = 0; mt < 2; ++mt)
#pragma unroll
          for (int rr = 0; rr < 4; ++rr) {
            int d = qi0 + mt * 16 + rr - kj; if (d < 0) d = -d;
            float e = fexp2(s[mt][kt][rr] + (d <= bandR ? C2 : 0.f));
            l_part[mt][rr] += e;
            Psw[mt * 16 + quad * 4 + rr][colp] = (bf16)e;
          }
      }
    } else {
#pragma unroll
      for (int kt = 0; kt < 2; ++kt) {
        int colp = (kt * 16 + l16 + 8 * quad) & 31;
#pragma unroll
        for (int mt = 0; mt < 2; ++mt)
#pragma unroll
          for (int rr = 0; rr < 4; ++rr) {
            float e = fexp2(s[mt][kt][rr]);
            l_part[mt][rr] += e;
            Psw[mt * 16 + quad * 4 + rr][colp] = (bf16)e;
          }
      }
    }

    bf16x8 ap[2];
#pragma unroll
    for (int mt = 0; mt < 2; ++mt)
      ap[mt] = *(const bf16x8*)&Psw[mt * 16 + l16][8 * ((quad + (l16 >> 2)) & 3)];
    __builtin_amdgcn_s_setprio(1);
#pragma unroll
    for (int nt = 0; nt < 4; ++nt) {
      bf16x8 bv = *(const bf16x8*)&Vt[nt * 16 + l16][(kh * 32 + quad * 8 + 16 * nt) & 63];
#pragma unroll
      for (int mt = 0; mt < 2; ++mt)
        acc[mt][nt] = __builtin_amdgcn_mfma_f32_16x16x32_bf16(ap[mt], bv, acc[mt][nt], 0, 0, 0);
    }
    __builtin_amdgcn_s_setprio(0);
  }

  // ---- epilogue: reduce l within quad, combine key-halves via LDS ----
  float lr[2][4];
#pragma unroll
  for (int mt = 0; mt < 2; ++mt)
#pragma unroll
    for (int rr = 0; rr < 4; ++rr) {
      float t = l_part[mt][rr];
      t += __shfl_xor(t, 1);
      t += __shfl_xor(t, 2);
      t += __shfl_xor(t, 4);
      t += __shfl_xor(t, 8);
      lr[mt][rr] = t;
    }
  __syncthreads();
  if (kh == 0) {
#pragma unroll
    for (int mt = 0; mt < 2; ++mt)
#pragma unroll
      for (int nt = 0; nt < 4; ++nt)
#pragma unroll
        for (int rr = 0; rr < 4; ++rr)
          Obuf[(qh * 32 + mt * 16 + quad * 4 + rr) * 66 + nt * 16 + l16] = acc[mt][nt][rr];
    if (l16 == 0) {
#pragma unroll
      for (int mt = 0; mt < 2; ++mt)
#pragma unroll
        for (int rr = 0; rr < 4; ++rr)
          l0_arr[qh * 32 + mt * 16 + quad * 4 + rr] = lr[mt][rr];
    }
  }
  __syncthreads();
  if (kh == 1) {
#pragma unroll
    for (int mt = 0; mt < 2; ++mt)
#pragma unroll
      for (int rr = 0; rr < 4; ++rr) {
        int ql = qh * 32 + mt * 16 + quad * 4 + rr;
        float lt = lr[mt][rr] + l0_arr[ql];
        int qrow = qt * 64 + ql;
#pragma unroll
        for (int nt = 0; nt < 4; ++nt) {
          float o = (acc[mt][nt][rr] + Obuf[ql * 66 + nt * 16 + l16]) / lt;
          Ob[(size_t)qrow * 768 + nt * 16 + l16] = (bf16)o;
        }
      }
  }
}

// ---------------------------------------------------------------------------
template <typename TY, typename TR, typename TO>
__global__ __launch_bounds__(256) void k_add_ln(const TY* __restrict__ Y,
                                                const TR* __restrict__ X,
                                                const float* __restrict__ g,
                                                const float* __restrict__ b,
                                                TO* __restrict__ out) {
  int wave = threadIdx.x >> 6, lane = threadIdx.x & 63;
  int row = blockIdx.x * 4 + wave;
  const TY* y = Y + (size_t)row * 768;
  const TR* x = X + (size_t)row * 768;
  float v[12];
  float s = 0.f, s2 = 0.f;
#pragma unroll
  for (int c = 0; c < 3; ++c) {
    int idx = c * 256 + lane * 4;
    float yv[4], xv[4];
    if constexpr (__is_same(TY, float)) {
      float4 t = *(const float4*)(y + idx);
      yv[0] = t.x; yv[1] = t.y; yv[2] = t.z; yv[3] = t.w;
    } else {
      bf16x4 t = *(const bf16x4*)(y + idx);
#pragma unroll
      for (int i = 0; i < 4; ++i) yv[i] = (float)t[i];
    }
    if constexpr (__is_same(TR, float)) {
      float4 t = *(const float4*)(x + idx);
      xv[0] = t.x; xv[1] = t.y; xv[2] = t.z; xv[3] = t.w;
    } else {
      bf16x4 t = *(const bf16x4*)(x + idx);
#pragma unroll
      for (int i = 0; i < 4; ++i) xv[i] = (float)t[i];
    }
#pragma unroll
    for (int i = 0; i < 4; ++i) {
      float t = yv[i] + xv[i];
      v[c * 4 + i] = t; s += t; s2 += t * t;
    }
  }
#pragma unroll
  for (int off = 32; off > 0; off >>= 1) { s += __shfl_xor(s, off); s2 += __shfl_xor(s2, off); }
  float mean = s * (1.f / 768.f);
  float var = fmaxf(s2 * (1.f / 768.f) - mean * mean, 0.f);
  float inv = rsqrtf(var + 1e-12f);
  TO* o = out + (size_t)row * 768;
#pragma unroll
  for (int c = 0; c < 3; ++c) {
    int idx = c * 256 + lane * 4;
    float4 gv = *(const float4*)(g + idx);
    float4 bv = *(const float4*)(b + idx);
    float r0 = (v[c * 4 + 0] - mean) * inv * gv.x + bv.x;
    float r1 = (v[c * 4 + 1] - mean) * inv * gv.y + bv.y;
    float r2 = (v[c * 4 + 2] - mean) * inv * gv.z + bv.z;
    float r3 = (v[c * 4 + 3] - mean) * inv * gv.w + bv.w;
    if constexpr (__is_same(TO, float)) {
      float4 ov = {r0, r1, r2, r3};
      *(float4*)(o + idx) = ov;
    } else {
      bf16x4 ov;
      ov[0] = (bf16)r0; ov[1] = (bf16)r1; ov[2] = (bf16)r2; ov[3] = (bf16)r3;
      *(bf16x4*)(o + idx) = ov;
    }
  }
}

// ---------------------------------------------------------------------------
extern "C" void kernel_launch(void* const* d_in, const int* in_sizes, int n_in,
                              void* d_out, int out_size, void* d_ws, size_t ws_size,
                              hipStream_t stream) {
  (void)in_sizes; (void)n_in; (void)out_size; (void)ws_size;
  const float* X     = (const float*)d_in[0];
  const float* tag   = (const float*)d_in[1];
  const float* sa_wq = (const float*)d_in[2];
  const float* sa_bq = (const float*)d_in[3];
  const float* sa_wk = (const float*)d_in[4];
  const float* sa_bk = (const float*)d_in[5];
  const float* sa_wv = (const float*)d_in[6];
  const float* sa_bv = (const float*)d_in[7];
  const float* sa_wo = (const float*)d_in[8];
  const float* sa_bo = (const float*)d_in[9];
  const float* sa_lg = (const float*)d_in[10];
  const float* sa_lb = (const float*)d_in[11];
  const float* ca_wq = (const float*)d_in[12];
  const float* ca_bq = (const float*)d_in[13];
  const float* ca_wk = (const float*)d_in[14];
  const float* ca_bk = (const float*)d_in[15];
  const float* ca_wv = (const float*)d_in[16];
  const float* ca_bv = (const float*)d_in[17];
  const float* ca_wo = (const float*)d_in[18];
  const float* ca_bo = (const float*)d_in[19];
  const float* ca_lg = (const float*)d_in[20];
  const float* ca_lb = (const float*)d_in[21];
  const float* ff_w1 = (const float*)d_in[22];
  const float* ff_b1 = (const float*)d_in[23];
  const float* ff_w2 = (const float*)d_in[24];
  const float* ff_b2 = (const float*)d_in[25];
  const float* ff_lg = (const float*)d_in[26];
  const float* ff_lb = (const float*)d_in[27];

  float* outf = (float*)d_out;
  bf16* outb = (bf16*)d_out;
  const size_t SLOT = (size_t)4096 * 768;

  // ---- ws: 34.60 MB ----
  bf16* BIG   = (bf16*)d_ws;                    // 4096x2304
  bf16* slotA = BIG + (size_t)4096 * 2304;      // residual chain
  bf16* Wall  = slotA + SLOT;                   // 3072x768
  bf16* W2    = Wall + (size_t)3072 * 768;      // 768x3072
  bf16* tagp  = W2;
  bf16* k2v2  = W2 + (size_t)128 * 768;
  float* bQKV = (float*)(W2 + (size_t)128 * 768 + (size_t)128 * 1536);
  float* bKV2 = bQKV + 2304;

  dim3 blk(256);

  k_concat3<<<dim3(9), blk, 0, stream>>>(sa_bq, sa_bk, sa_bv, bQKV, 768);
  k_concat3<<<dim3(6), blk, 0, stream>>>(ca_bk, ca_bv, nullptr, bKV2, 768);
  k_pad_tags<<<dim3(384), blk, 0, stream>>>(tag, tagp);

  // ---- self-attention ----
  k_transpose4<<<dim3(12, 12, 4), blk, 0, stream>>>(sa_wq, sa_wk, sa_wv, sa_wo, Wall);
  k_gemm<128, 1, true, false><<<dim3(32, 18), blk, 0, stream>>>(X, Wall, bQKV, BIG,
                                                                4096, 2304, 768, 0);  // QKV
  k_attn_mfma<<<dim3(32, 24), blk, 0, stream>>>(BIG, 2304, BIG + 768, BIG + 1536, 2304,
                                                outb, 2048, 2048, (long long)2048 * 2304, 50);
  k_gemm<64, 2, false, false><<<dim3(64, 6), blk, 0, stream>>>(outb, Wall + (size_t)2304 * 768,
                                                               sa_bo, slotA, 4096, 768, 768, 0);  // y1
  k_add_ln<bf16, float, bf16><<<dim3(1024), blk, 0, stream>>>(slotA, X, sa_lg, sa_lb, slotA);

  // ---- cross-attention ----
  k_transpose4<<<dim3(12, 12, 4), blk, 0, stream>>>(ca_wq, ca_wk, ca_wv, ca_wo, Wall);
  k_gemm<64, 2, false, false><<<dim3(64, 6), blk, 0, stream>>>(slotA, Wall, ca_bq, BIG,
                                                               4096, 768, 768, 0);  // Q2
  k_gemm<64, 2, false, false><<<dim3(2, 12), blk, 0, stream>>>(tagp, Wall + (size_t)768 * 768,
                                                               bKV2, k2v2, 128, 1536, 768, 0);  // K2V2
  k_attn_mfma<<<dim3(32, 24), blk, 0, stream>>>(BIG, 768, k2v2, k2v2 + 768, 1536,
                                                outb, 2048, 64, 0, -1);
  k_gemm<64, 2, false, false><<<dim3(64, 6), blk, 0, stream>>>(outb, Wall + (size_t)2304 * 768,
                                                               ca_bo, BIG + SLOT, 4096, 768, 768, 0);  // y2
  k_add_ln<bf16, bf16, bf16><<<dim3(1024), blk, 0, stream>>>(BIG + SLOT, slotA, ca_lg, ca_lb, slotA);

  // ---- FFN: 2 M-chunks of 2048 rows via BIG ----
  k_transpose<<<dim3(48, 12), blk, 0, stream>>>(ff_w1, Wall, 768, 3072);  // ff1t [3072][768]
  k_transpose<<<dim3(12, 48), blk, 0, stream>>>(ff_w2, W2, 3072, 768);    // ff2t [768][3072]
  for (int mc = 0; mc < 2; ++mc) {
    const bf16* a2 = slotA + (size_t)mc * 2048 * 768;
    float* yo = outf + (size_t)mc * 2048 * 768;
    k_gemm<128, 2, false, false><<<dim3(16, 24), blk, 0, stream>>>(a2, Wall, ff_b1, BIG,
                                                                   2048, 3072, 768, 1);  // gelu inter
    k_gemm<64, 2, false, true><<<dim3(32, 6), blk, 0, stream>>>(BIG, W2, ff_b2, yo,
                                                                2048, 768, 3072, 0);     // y3 fp32
    k_add_ln<float, bf16, float><<<dim3(512), blk, 0, stream>>>(yo, a2, ff_lg, ff_lb, yo);
  }
}

// Round 5
// 397.149 us; speedup vs baseline: 1.1894x; 1.1726x over previous
//
#include <hip/hip_runtime.h>
#include <cstdint>
#include <cstddef>

// B=2, S=2048, D=768, H=12, DH=64, T=64, R=50, FF=3072
// fp32 I/O, bf16 MFMA internals.
// R15: GEMM occupancy pass (attn untouched from R14 — plateaued at 60us;
// non-attn remainder is ~405us = 87% and the N=768 GEMMs run 0.75-1.5
// blocks/CU). Changes:
//  - k_gemm templated on BN (64|128): BN=64 doubles N-blocks for N=768
//    GEMMs (y1/Q2/y2: 384->768 blocks = 3/CU).
//  - ff2 split-K x2 via blockIdx.z (K=3072 -> 2x1536): partial z=1 into the
//    free 3rd SLOT of BIG (f32), summed in the FFN add_ln. 192->768 blocks.
//  - ff1 BM 128->64: 384->768 blocks.
//  - QKV BM 128->64 (AF32 path: single row-half prefetch): 576->1152 blocks.

typedef __bf16 bf16;
typedef __bf16 bf16x8 __attribute__((ext_vector_type(8)));
typedef __bf16 bf16x4 __attribute__((ext_vector_type(4)));
typedef __bf16 bf16x2 __attribute__((ext_vector_type(2)));
typedef float  floatx4 __attribute__((ext_vector_type(4)));

__device__ __forceinline__ void glds16(const bf16* g, bf16* l) {
  __builtin_amdgcn_global_load_lds((const __attribute__((address_space(1))) void*)g,
                                   (__attribute__((address_space(3))) void*)l, 16, 0, 0);
}

__device__ __forceinline__ float fexp2(float x) {
  float r;
  asm("v_exp_f32 %0, %1" : "=v"(r) : "v"(x));
  return r;
}

// ---------------------------------------------------------------------------
__global__ __launch_bounds__(256) void k_concat3(const float* __restrict__ a,
                                                 const float* __restrict__ b,
                                                 const float* __restrict__ c,
                                                 float* __restrict__ o, int seg) {
  int i = blockIdx.x * 256 + threadIdx.x;
  int s = i / seg, j = i - s * seg;
  const float* p = s == 0 ? a : (s == 1 ? b : c);
  o[i] = p[j];
}

__global__ void k_pad_tags(const float* __restrict__ tag, bf16* __restrict__ out) {
  int i = blockIdx.x * 256 + threadIdx.x;
  if (i < 64 * 768) out[i] = (bf16)tag[i];
  else if (i < 128 * 768) out[i] = (bf16)0.f;
}

// ---------------------------------------------------------------------------
__global__ __launch_bounds__(256) void k_transpose(const float* __restrict__ W,
                                                   bf16* __restrict__ Wt,
                                                   int K, int N) {
  __shared__ bf16 tile[64][72];
  int n0 = blockIdx.x * 64, k0 = blockIdx.y * 64;
  int t = threadIdx.x;
  int r = t >> 2, cg = (t & 3) * 16;
  const float* src = W + (size_t)(k0 + r) * N + n0 + cg;
  float tmp[16];
  *(float4*)&tmp[0]  = *(const float4*)(src);
  *(float4*)&tmp[4]  = *(const float4*)(src + 4);
  *(float4*)&tmp[8]  = *(const float4*)(src + 8);
  *(float4*)&tmp[12] = *(const float4*)(src + 12);
#pragma unroll
  for (int i = 0; i < 16; ++i) tile[r][cg + i] = (bf16)tmp[i];
  __syncthreads();
  bf16* dst = Wt + (size_t)(n0 + r) * K + k0 + cg;
#pragma unroll
  for (int g = 0; g < 2; ++g) {
    bf16x8 pack;
#pragma unroll
    for (int i = 0; i < 8; ++i) pack[i] = tile[cg + g * 8 + i][r];
    *(bf16x8*)(dst + g * 8) = pack;
  }
}

__global__ __launch_bounds__(256) void k_transpose4(const float* __restrict__ W0,
                                                    const float* __restrict__ W1,
                                                    const float* __restrict__ W2w,
                                                    const float* __restrict__ W3,
                                                    bf16* __restrict__ Wt) {
  __shared__ bf16 tile[64][72];
  int z = blockIdx.z;
  const float* W = z == 0 ? W0 : (z == 1 ? W1 : (z == 2 ? W2w : W3));
  bf16* dstb = Wt + (size_t)z * 768 * 768;
  int n0 = blockIdx.x * 64, k0 = blockIdx.y * 64;
  int t = threadIdx.x;
  int r = t >> 2, cg = (t & 3) * 16;
  const float* src = W + (size_t)(k0 + r) * 768 + n0 + cg;
  float tmp[16];
  *(float4*)&tmp[0]  = *(const float4*)(src);
  *(float4*)&tmp[4]  = *(const float4*)(src + 4);
  *(float4*)&tmp[8]  = *(const float4*)(src + 8);
  *(float4*)&tmp[12] = *(const float4*)(src + 12);
#pragma unroll
  for (int i = 0; i < 16; ++i) tile[r][cg + i] = (bf16)tmp[i];
  __syncthreads();
  bf16* dst = dstb + (size_t)(n0 + r) * 768 + k0 + cg;
#pragma unroll
  for (int g = 0; g < 2; ++g) {
    bf16x8 pack;
#pragma unroll
    for (int i = 0; i < 8; ++i) pack[i] = tile[cg + g * 8 + i][r];
    *(bf16x8*)(dst + g * 8) = pack;
  }
}

// ---------------------------------------------------------------------------
// GEMM: C[M,N] = A[M,K] @ Bt[N,K]^T + bias. BMxBN tile, KS BK=32 sub-tiles
// per barrier pair. glds width-16 staging. AF32: fp32 A cvt in regs (KS=1).
// CF32: fp32 C out. ld = K-stride of A/Bt rows; blockIdx.z selects a K-chunk
// of length K at offset z*K (split-K): z=0 -> Cv (+bias), z=1 -> Cv2 (raw).
template <int BM, int BN, int KS, bool AF32, bool CF32>
__global__ __launch_bounds__(256) void k_gemm(const void* __restrict__ Av,
                                              const bf16* __restrict__ Bt,
                                              const float* __restrict__ bias,
                                              void* __restrict__ Cv,
                                              void* __restrict__ Cv2,
                                              int M, int N, int K, int ld, int act) {
  constexpr int MT = BM / 32;
  constexpr int NT = BN / 32;
  __shared__ bf16 As[KS][BM * 32];
  __shared__ bf16 Bs[KS][BN * 32];
  int tid = threadIdx.x;
  int lane = tid & 63, wave = tid >> 6;
  int l16 = lane & 15, quad = lane >> 4;
  int wm = wave & 1, wn = wave >> 1;
  int m0 = blockIdx.x * BM, n0 = blockIdx.y * BN;
  int z = blockIdx.z;
  int arow = tid >> 2, acol = (tid & 3) * 8;
  int ldst = arow * 32 + acol;  // = tid*8 elems (lane-contiguous glds pattern)

  const bf16* Ab = (const bf16*)Av;
  const float* Af = (const float*)Av;
  const bf16* Ap = Ab + (size_t)(m0 + arow) * ld + z * K + acol;
  const float* Apf = Af + (size_t)(m0 + arow) * ld + acol;  // AF32 never split
  const bf16* Bp = Bt + (size_t)(n0 + arow) * ld + z * K + acol;

  floatx4 acc[MT][NT];
#pragma unroll
  for (int i = 0; i < MT; ++i)
#pragma unroll
    for (int j = 0; j < NT; ++j) acc[i][j] = floatx4{0.f, 0.f, 0.f, 0.f};

  float4 p0a, p0b, p1a, p1b;
  if constexpr (AF32) {
    p0a = *(const float4*)(Apf);
    p0b = *(const float4*)(Apf + 4);
    if constexpr (BM == 128) {
      p1a = *(const float4*)(Apf + (size_t)64 * ld);
      p1b = *(const float4*)(Apf + (size_t)64 * ld + 4);
    }
  }

  for (int k = 0; k < K; k += 32 * KS) {
    __syncthreads();
#pragma unroll
    for (int ks = 0; ks < KS; ++ks) {
      glds16(Bp + k + ks * 32, &Bs[ks][ldst]);
      if constexpr (BN == 128) glds16(Bp + (size_t)64 * ld + k + ks * 32, &Bs[ks][ldst + 2048]);
    }
    if constexpr (AF32) {
      bf16x8 c0;
      c0[0] = (bf16)p0a.x; c0[1] = (bf16)p0a.y; c0[2] = (bf16)p0a.z; c0[3] = (bf16)p0a.w;
      c0[4] = (bf16)p0b.x; c0[5] = (bf16)p0b.y; c0[6] = (bf16)p0b.z; c0[7] = (bf16)p0b.w;
      *(bf16x8*)&As[0][ldst] = c0;
      if constexpr (BM == 128) {
        bf16x8 c1;
        c1[0] = (bf16)p1a.x; c1[1] = (bf16)p1a.y; c1[2] = (bf16)p1a.z; c1[3] = (bf16)p1a.w;
        c1[4] = (bf16)p1b.x; c1[5] = (bf16)p1b.y; c1[6] = (bf16)p1b.z; c1[7] = (bf16)p1b.w;
        *(bf16x8*)&As[0][ldst + 2048] = c1;
      }
    } else {
#pragma unroll
      for (int ks = 0; ks < KS; ++ks) {
        glds16(Ap + k + ks * 32, &As[ks][ldst]);
        if constexpr (BM == 128) glds16(Ap + (size_t)64 * ld + k + ks * 32, &As[ks][ldst + 2048]);
      }
    }
    __syncthreads();
    if constexpr (AF32) {
      if (k + 32 < K) {
        p0a = *(const float4*)(Apf + k + 32);
        p0b = *(const float4*)(Apf + k + 36);
        if constexpr (BM == 128) {
          p1a = *(const float4*)(Apf + (size_t)64 * ld + k + 32);
          p1b = *(const float4*)(Apf + (size_t)64 * ld + k + 36);
        }
      }
    }
#pragma unroll
    for (int ks = 0; ks < KS; ++ks) {
      bf16x8 a_frag[MT], b_frag[NT];
#pragma unroll
      for (int mt = 0; mt < MT; ++mt)
        a_frag[mt] = *(const bf16x8*)&As[ks][(wm * (BM / 2) + mt * 16 + l16) * 32 + quad * 8];
#pragma unroll
      for (int nt = 0; nt < NT; ++nt)
        b_frag[nt] = *(const bf16x8*)&Bs[ks][(wn * (BN / 2) + nt * 16 + l16) * 32 + quad * 8];
#pragma unroll
      for (int mt = 0; mt < MT; ++mt)
#pragma unroll
        for (int nt = 0; nt < NT; ++nt)
          acc[mt][nt] = __builtin_amdgcn_mfma_f32_16x16x32_bf16(a_frag[mt], b_frag[nt], acc[mt][nt], 0, 0, 0);
    }
  }

  void* Co = (z == 0) ? Cv : Cv2;
#pragma unroll
  for (int nt = 0; nt < NT; ++nt) {
    int col = n0 + wn * (BN / 2) + nt * 16 + l16;
    float bv = (z == 0) ? bias[col] : 0.f;
#pragma unroll
    for (int mt = 0; mt < MT; ++mt) {
#pragma unroll
      for (int r = 0; r < 4; ++r) {
        int row = m0 + wm * (BM / 2) + mt * 16 + quad * 4 + r;
        float v = acc[mt][nt][r] + bv;
        if (act) v = 0.5f * v * (1.f + erff(v * 0.70710678118654752f));
        if constexpr (CF32) ((float*)Co)[(size_t)row * N + col] = v;
        else ((bf16*)Co)[(size_t)row * N + col] = (bf16)v;
      }
    }
  }
}

// ---------------------------------------------------------------------------
// MFMA flash attention, max-free streaming softmax. QBLK=64 rows per block.
// Wave w: q-half qh=w&1 (32 rows), key-half kh=w>>1 (32 keys/chunk).
// Q pre-scaled by log2e/8, fragments direct from global (no Qs LDS stage).
// K/V double-buffered in LDS: ONE barrier per chunk (R14).
__global__ __launch_bounds__(256) void k_attn_mfma(const bf16* __restrict__ Q, int ldq,
                                                   const bf16* __restrict__ Kp,
                                                   const bf16* __restrict__ Vp, int ldkv,
                                                   bf16* __restrict__ O,
                                                   int S, int Skv,
                                                   long long kv_bstride, int bandR) {
  const int NH = 12;
  int qt = blockIdx.x, bh = blockIdx.y;
  int bb = bh / NH, h = bh % NH;
  const bf16* Qb = Q + (size_t)bb * S * ldq + h * 64;
  const bf16* Kb = Kp + (size_t)bb * kv_bstride + h * 64;
  const bf16* Vb = Vp + (size_t)bb * kv_bstride + h * 64;
  bf16* Ob = O + (size_t)bb * S * 768 + h * 64;

  // LDS: Ks[2][64][72] @0 (18432), Vt[2][64][72] @18432 (18432),
  // Psw 4x[32][40] @36864 (10240) = 47104 B.
  // Epilogue overlay: Obuf[64][66] f32 @0 (16896), l0[64] @16896.
  __shared__ __align__(16) char smem[47104];
  float* Obuf = (float*)smem;
  float* l0_arr = (float*)(smem + 16896);

  int tid = threadIdx.x, wave = tid >> 6, lane = tid & 63;
  int quad = lane >> 4, l16 = lane & 15;
  int qh = wave & 1, kh = wave >> 1;
  bf16 (*Psw)[40] = (bf16(*)[40])(smem + 36864 + wave * 2560);

  const float C1 = 0.18033688f;   // log2(e)/8
  const float C2 = 1.44269504f;   // log2(e)

  int r = tid >> 2, cg = (tid & 3) * 16;  // K staging: 64 rows x 16 cols/lane
  int vk0 = 2 * (tid & 31);
  int vd0 = 8 * (tid >> 5);
  int vcol = (vk0 + 16 * (vd0 >> 4)) & 63;

  // Q fragments direct from global (once per block), pre-scaled by C1.
  bf16x8 aq[2][2];
#pragma unroll
  for (int mt = 0; mt < 2; ++mt) {
    const bf16* qsrc = Qb + (size_t)(qt * 64 + qh * 32 + mt * 16 + l16) * ldq;
#pragma unroll
    for (int ks = 0; ks < 2; ++ks) {
      bf16x8 t = *(const bf16x8*)(qsrc + ks * 32 + quad * 8);
#pragma unroll
      for (int e = 0; e < 8; ++e) t[e] = (bf16)((float)t[e] * C1);
      aq[mt][ks] = t;
    }
  }

  // prefetch regs for K/V chunk staging
  bf16x8 kr0, kr1, vr0, vr1;
  {
    const bf16* ksrc = Kb + (size_t)r * ldkv + cg;
    kr0 = *(const bf16x8*)ksrc;
    kr1 = *(const bf16x8*)(ksrc + 8);
    const bf16* vsrc = Vb + (size_t)vk0 * ldkv + vd0;
    vr0 = *(const bf16x8*)vsrc;
    vr1 = *(const bf16x8*)(vsrc + ldkv);
  }

  float l_part[2][4];
  floatx4 acc[2][4];
#pragma unroll
  for (int mt = 0; mt < 2; ++mt)
#pragma unroll
    for (int j = 0; j < 4; ++j) {
      l_part[mt][j] = 0.f;
      acc[mt][j] = floatx4{0.f, 0.f, 0.f, 0.f};
    }

  int qi0 = qt * 64 + qh * 32 + quad * 4;

  for (int kc = 0; kc < Skv; kc += 64) {
    int cur = (kc >> 6) & 1;
    bf16 (*Ks)[72] = (bf16(*)[72])(smem + cur * 9216);
    bf16 (*Vt)[72] = (bf16(*)[72])(smem + 18432 + cur * 9216);
    // write staged chunk to buf[cur] (prior reads fenced by iter c-1 barrier)
    *(bf16x8*)&Ks[r][cg] = kr0;
    *(bf16x8*)&Ks[r][cg + 8] = kr1;
#pragma unroll
    for (int e = 0; e < 8; ++e) {
      bf16x2 p; p[0] = vr0[e]; p[1] = vr1[e];
      *(bf16x2*)&Vt[vd0 + e][vcol] = p;
    }
    // issue next chunk's loads (fly under this chunk's compute)
    if (kc + 64 < Skv) {
      const bf16* ksrc = Kb + (size_t)(kc + 64 + r) * ldkv + cg;
      kr0 = *(const bf16x8*)ksrc;
      kr1 = *(const bf16x8*)(ksrc + 8);
      const bf16* vsrc = Vb + (size_t)(kc + 64 + vk0) * ldkv + vd0;
      vr0 = *(const bf16x8*)vsrc;
      vr1 = *(const bf16x8*)(vsrc + ldkv);
    }
    __syncthreads();

    floatx4 s[2][2];
    __builtin_amdgcn_s_setprio(1);
#pragma unroll
    for (int kt = 0; kt < 2; ++kt) {
      bf16x8 bk0 = *(const bf16x8*)&Ks[kh * 32 + kt * 16 + l16][quad * 8];
      bf16x8 bk1 = *(const bf16x8*)&Ks[kh * 32 + kt * 16 + l16][32 + quad * 8];
#pragma unroll
      for (int mt = 0; mt < 2; ++mt) {
        floatx4 c = {0.f, 0.f, 0.f, 0.f};
        c = __builtin_amdgcn_mfma_f32_16x16x32_bf16(aq[mt][0], bk0, c, 0, 0, 0);
        c = __builtin_amdgcn_mfma_f32_16x16x32_bf16(aq[mt][1], bk1, c, 0, 0, 0);
        s[mt][kt] = c;
      }
    }
    __builtin_amdgcn_s_setprio(0);

    bool masked = (bandR >= 0) && (kc <= qt * 64 + 63 + bandR) &&
                  (kc + 63 >= qt * 64 - bandR);
    if (masked) {
#pragma unroll
      for (int kt = 0; kt < 2; ++kt) {
        int kj = kc + kh * 32 + kt * 16 + l16;
        int colp = (kt * 16 + l16 + 8 * quad) & 31;
#pragma unroll
        for (int mt = 0; mt < 2; ++mt)
#pragma unroll
          for (int rr = 0; rr < 4; ++rr) {
            int d = qi0 + mt * 16 + rr - kj; if (d < 0) d = -d;
            float e = fexp2(s[mt][kt][rr] + (d <= bandR ? C2 : 0.f));
            l_part[mt][rr] += e;
            Psw[mt * 16 + quad * 4 + rr][colp] = (bf16)e;
          }
      }
    } else {
#pragma unroll
      for (int kt = 0; kt < 2; ++kt) {
        int colp = (kt * 16 + l16 + 8 * quad) & 31;
#pragma unroll
        for (int mt = 0; mt < 2; ++mt)
#pragma unroll
          for (int rr = 0; rr < 4; ++rr) {
            float e = fexp2(s[mt][kt][rr]);
            l_part[mt][rr] += e;
            Psw[mt * 16 + quad * 4 + rr][colp] = (bf16)e;
          }
      }
    }

    bf16x8 ap[2];
#pragma unroll
    for (int mt = 0; mt < 2; ++mt)
      ap[mt] = *(const bf16x8*)&Psw[mt * 16 + l16][8 * ((quad + (l16 >> 2)) & 3)];
    __builtin_amdgcn_s_setprio(1);
#pragma unroll
    for (int nt = 0; nt < 4; ++nt) {
      bf16x8 bv = *(const bf16x8*)&Vt[nt * 16 + l16][(kh * 32 + quad * 8 + 16 * nt) & 63];
#pragma unroll
      for (int mt = 0; mt < 2; ++mt)
        acc[mt][nt] = __builtin_amdgcn_mfma_f32_16x16x32_bf16(ap[mt], bv, acc[mt][nt], 0, 0, 0);
    }
    __builtin_amdgcn_s_setprio(0);
  }

  // ---- epilogue: reduce l within quad, combine key-halves via LDS ----
  float lr[2][4];
#pragma unroll
  for (int mt = 0; mt < 2; ++mt)
#pragma unroll
    for (int rr = 0; rr < 4; ++rr) {
      float t = l_part[mt][rr];
      t += __shfl_xor(t, 1);
      t += __shfl_xor(t, 2);
      t += __shfl_xor(t, 4);
      t += __shfl_xor(t, 8);
      lr[mt][rr] = t;
    }
  __syncthreads();
  if (kh == 0) {
#pragma unroll
    for (int mt = 0; mt < 2; ++mt)
#pragma unroll
      for (int nt = 0; nt < 4; ++nt)
#pragma unroll
        for (int rr = 0; rr < 4; ++rr)
          Obuf[(qh * 32 + mt * 16 + quad * 4 + rr) * 66 + nt * 16 + l16] = acc[mt][nt][rr];
    if (l16 == 0) {
#pragma unroll
      for (int mt = 0; mt < 2; ++mt)
#pragma unroll
        for (int rr = 0; rr < 4; ++rr)
          l0_arr[qh * 32 + mt * 16 + quad * 4 + rr] = lr[mt][rr];
    }
  }
  __syncthreads();
  if (kh == 1) {
#pragma unroll
    for (int mt = 0; mt < 2; ++mt)
#pragma unroll
      for (int rr = 0; rr < 4; ++rr) {
        int ql = qh * 32 + mt * 16 + quad * 4 + rr;
        float lt = lr[mt][rr] + l0_arr[ql];
        int qrow = qt * 64 + ql;
#pragma unroll
        for (int nt = 0; nt < 4; ++nt) {
          float o = (acc[mt][nt][rr] + Obuf[ql * 66 + nt * 16 + l16]) / lt;
          Ob[(size_t)qrow * 768 + nt * 16 + l16] = (bf16)o;
        }
      }
  }
}

// ---------------------------------------------------------------------------
// Y + X (+ optional f32 partial Y2) -> LayerNorm -> out.
template <typename TY, typename TR, typename TO>
__global__ __launch_bounds__(256) void k_add_ln(const TY* __restrict__ Y,
                                                const TR* __restrict__ X,
                                                const float* __restrict__ Y2,
                                                const float* __restrict__ g,
                                                const float* __restrict__ b,
                                                TO* __restrict__ out) {
  int wave = threadIdx.x >> 6, lane = threadIdx.x & 63;
  int row = blockIdx.x * 4 + wave;
  const TY* y = Y + (size_t)row * 768;
  const TR* x = X + (size_t)row * 768;
  float v[12];
  float s = 0.f, s2 = 0.f;
#pragma unroll
  for (int c = 0; c < 3; ++c) {
    int idx = c * 256 + lane * 4;
    float yv[4], xv[4];
    if constexpr (__is_same(TY, float)) {
      float4 t = *(const float4*)(y + idx);
      yv[0] = t.x; yv[1] = t.y; yv[2] = t.z; yv[3] = t.w;
    } else {
      bf16x4 t = *(const bf16x4*)(y + idx);
#pragma unroll
      for (int i = 0; i < 4; ++i) yv[i] = (float)t[i];
    }
    if constexpr (__is_same(TR, float)) {
      float4 t = *(const float4*)(x + idx);
      xv[0] = t.x; xv[1] = t.y; xv[2] = t.z; xv[3] = t.w;
    } else {
      bf16x4 t = *(const bf16x4*)(x + idx);
#pragma unroll
      for (int i = 0; i < 4; ++i) xv[i] = (float)t[i];
    }
    if (Y2 != nullptr) {
      float4 t2 = *(const float4*)(Y2 + (size_t)row * 768 + idx);
      xv[0] += t2.x; xv[1] += t2.y; xv[2] += t2.z; xv[3] += t2.w;
    }
#pragma unroll
    for (int i = 0; i < 4; ++i) {
      float t = yv[i] + xv[i];
      v[c * 4 + i] = t; s += t; s2 += t * t;
    }
  }
#pragma unroll
  for (int off = 32; off > 0; off >>= 1) { s += __shfl_xor(s, off); s2 += __shfl_xor(s2, off); }
  float mean = s * (1.f / 768.f);
  float var = fmaxf(s2 * (1.f / 768.f) - mean * mean, 0.f);
  float inv = rsqrtf(var + 1e-12f);
  TO* o = out + (size_t)row * 768;
#pragma unroll
  for (int c = 0; c < 3; ++c) {
    int idx = c * 256 + lane * 4;
    float4 gv = *(const float4*)(g + idx);
    float4 bv = *(const float4*)(b + idx);
    float r0 = (v[c * 4 + 0] - mean) * inv * gv.x + bv.x;
    float r1 = (v[c * 4 + 1] - mean) * inv * gv.y + bv.y;
    float r2 = (v[c * 4 + 2] - mean) * inv * gv.z + bv.z;
    float r3 = (v[c * 4 + 3] - mean) * inv * gv.w + bv.w;
    if constexpr (__is_same(TO, float)) {
      float4 ov = {r0, r1, r2, r3};
      *(float4*)(o + idx) = ov;
    } else {
      bf16x4 ov;
      ov[0] = (bf16)r0; ov[1] = (bf16)r1; ov[2] = (bf16)r2; ov[3] = (bf16)r3;
      *(bf16x4*)(o + idx) = ov;
    }
  }
}

// ---------------------------------------------------------------------------
extern "C" void kernel_launch(void* const* d_in, const int* in_sizes, int n_in,
                              void* d_out, int out_size, void* d_ws, size_t ws_size,
                              hipStream_t stream) {
  (void)in_sizes; (void)n_in; (void)out_size; (void)ws_size;
  const float* X     = (const float*)d_in[0];
  const float* tag   = (const float*)d_in[1];
  const float* sa_wq = (const float*)d_in[2];
  const float* sa_bq = (const float*)d_in[3];
  const float* sa_wk = (const float*)d_in[4];
  const float* sa_bk = (const float*)d_in[5];
  const float* sa_wv = (const float*)d_in[6];
  const float* sa_bv = (const float*)d_in[7];
  const float* sa_wo = (const float*)d_in[8];
  const float* sa_bo = (const float*)d_in[9];
  const float* sa_lg = (const float*)d_in[10];
  const float* sa_lb = (const float*)d_in[11];
  const float* ca_wq = (const float*)d_in[12];
  const float* ca_bq = (const float*)d_in[13];
  const float* ca_wk = (const float*)d_in[14];
  const float* ca_bk = (const float*)d_in[15];
  const float* ca_wv = (const float*)d_in[16];
  const float* ca_bv = (const float*)d_in[17];
  const float* ca_wo = (const float*)d_in[18];
  const float* ca_bo = (const float*)d_in[19];
  const float* ca_lg = (const float*)d_in[20];
  const float* ca_lb = (const float*)d_in[21];
  const float* ff_w1 = (const float*)d_in[22];
  const float* ff_b1 = (const float*)d_in[23];
  const float* ff_w2 = (const float*)d_in[24];
  const float* ff_b2 = (const float*)d_in[25];
  const float* ff_lg = (const float*)d_in[26];
  const float* ff_lb = (const float*)d_in[27];

  float* outf = (float*)d_out;
  bf16* outb = (bf16*)d_out;
  const size_t SLOT = (size_t)4096 * 768;

  // ---- ws: 34.60 MB ----
  bf16* BIG   = (bf16*)d_ws;                    // 4096x2304 (3 SLOTs)
  bf16* slotA = BIG + (size_t)4096 * 2304;      // residual chain
  bf16* Wall  = slotA + SLOT;                   // 3072x768
  bf16* W2    = Wall + (size_t)3072 * 768;      // 768x3072
  bf16* tagp  = W2;
  bf16* k2v2  = W2 + (size_t)128 * 768;
  float* bQKV = (float*)(W2 + (size_t)128 * 768 + (size_t)128 * 1536);
  float* bKV2 = bQKV + 2304;
  float* P1   = (float*)(BIG + 2 * SLOT);       // ff2 split-K partial (3rd SLOT)

  dim3 blk(256);

  k_concat3<<<dim3(9), blk, 0, stream>>>(sa_bq, sa_bk, sa_bv, bQKV, 768);
  k_concat3<<<dim3(6), blk, 0, stream>>>(ca_bk, ca_bv, nullptr, bKV2, 768);
  k_pad_tags<<<dim3(384), blk, 0, stream>>>(tag, tagp);

  // ---- self-attention ----
  k_transpose4<<<dim3(12, 12, 4), blk, 0, stream>>>(sa_wq, sa_wk, sa_wv, sa_wo, Wall);
  k_gemm<64, 128, 1, true, false><<<dim3(64, 18), blk, 0, stream>>>(X, Wall, bQKV, BIG, nullptr,
                                                                    4096, 2304, 768, 768, 0);  // QKV
  k_attn_mfma<<<dim3(32, 24), blk, 0, stream>>>(BIG, 2304, BIG + 768, BIG + 1536, 2304,
                                                outb, 2048, 2048, (long long)2048 * 2304, 50);
  k_gemm<64, 64, 2, false, false><<<dim3(64, 12), blk, 0, stream>>>(outb, Wall + (size_t)2304 * 768,
                                                                    sa_bo, slotA, nullptr,
                                                                    4096, 768, 768, 768, 0);  // y1
  k_add_ln<bf16, float, bf16><<<dim3(1024), blk, 0, stream>>>(slotA, X, nullptr, sa_lg, sa_lb, slotA);

  // ---- cross-attention ----
  k_transpose4<<<dim3(12, 12, 4), blk, 0, stream>>>(ca_wq, ca_wk, ca_wv, ca_wo, Wall);
  k_gemm<64, 64, 2, false, false><<<dim3(64, 12), blk, 0, stream>>>(slotA, Wall, ca_bq, BIG, nullptr,
                                                                    4096, 768, 768, 768, 0);  // Q2
  k_gemm<64, 64, 2, false, false><<<dim3(2, 24), blk, 0, stream>>>(tagp, Wall + (size_t)768 * 768,
                                                                   bKV2, k2v2, nullptr,
                                                                   128, 1536, 768, 768, 0);  // K2V2
  k_attn_mfma<<<dim3(32, 24), blk, 0, stream>>>(BIG, 768, k2v2, k2v2 + 768, 1536,
                                                outb, 2048, 64, 0, -1);
  k_gemm<64, 64, 2, false, false><<<dim3(64, 12), blk, 0, stream>>>(outb, Wall + (size_t)2304 * 768,
                                                                    ca_bo, BIG + SLOT, nullptr,
                                                                    4096, 768, 768, 768, 0);  // y2
  k_add_ln<bf16, bf16, bf16><<<dim3(1024), blk, 0, stream>>>(BIG + SLOT, slotA, nullptr,
                                                             ca_lg, ca_lb, slotA);

  // ---- FFN: 2 M-chunks of 2048 rows via BIG (inter = first 2 SLOTs) ----
  k_transpose<<<dim3(48, 12), blk, 0, stream>>>(ff_w1, Wall, 768, 3072);  // ff1t [3072][768]
  k_transpose<<<dim3(12, 48), blk, 0, stream>>>(ff_w2, W2, 3072, 768);    // ff2t [768][3072]
  for (int mc = 0; mc < 2; ++mc) {
    const bf16* a2 = slotA + (size_t)mc * 2048 * 768;
    float* yo = outf + (size_t)mc * 2048 * 768;
    k_gemm<64, 128, 2, false, false><<<dim3(32, 24), blk, 0, stream>>>(a2, Wall, ff_b1, BIG, nullptr,
                                                                       2048, 3072, 768, 768, 1);  // gelu inter
    // ff2 split-K x2: z=0 -> yo (+bias), z=1 -> P1 (raw); summed in add_ln.
    k_gemm<64, 64, 2, false, true><<<dim3(32, 12, 2), blk, 0, stream>>>(BIG, W2, ff_b2, yo, P1,
                                                                        2048, 768, 1536, 3072, 0);
    k_add_ln<float, bf16, float><<<dim3(512), blk, 0, stream>>>(yo, a2, P1, ff_lg, ff_lb, yo);
  }
}